// Round 5
// baseline (903.354 us; speedup 1.0000x reference)
//
#include <hip/hip_runtime.h>
#include <hip/hip_bf16.h>

#define B_  64
#define T_  30
#define E_  300
#define H_  512
#define FD_ 512
#define V_  10000
#define NWG_FUSED 32

typedef __attribute__((ext_vector_type(8))) unsigned short ushort8_t;
typedef __attribute__((ext_vector_type(4))) unsigned short ushort4_t;
typedef __attribute__((ext_vector_type(8))) __bf16 bf16x8;
typedef __attribute__((ext_vector_type(4))) float f32x4;

__device__ __forceinline__ float b2f(unsigned short u) {
    union { unsigned int i; float f; } v;
    v.i = ((unsigned int)u) << 16;
    return v.f;
}
__device__ __forceinline__ unsigned short f2b(float f) {
    unsigned int x = __builtin_bit_cast(unsigned int, f);
    unsigned int r = x + 0x7FFFu + ((x >> 16) & 1u);
    return (unsigned short)(r >> 16);
}

__device__ __forceinline__ f32x4 mfma16(bf16x8 a, bf16x8 b, f32x4 c) {
    return __builtin_amdgcn_mfma_f32_16x16x32_bf16(a, b, c, 0, 0, 0);
}

// coherence-point (agent-scope, L2-bypassing) 16B load as two 8B atomic loads
__device__ __forceinline__ bf16x8 load_h16(const unsigned short* p) {
    unsigned long long a = __hip_atomic_load((const unsigned long long*)p,
                                             __ATOMIC_RELAXED, __HIP_MEMORY_SCOPE_AGENT);
    unsigned long long b = __hip_atomic_load((const unsigned long long*)(p + 4),
                                             __ATOMIC_RELAXED, __HIP_MEMORY_SCOPE_AGENT);
    union { unsigned long long q[2]; bf16x8 v; } u;
    u.q[0] = a; u.q[1] = b;
    return u.v;
}

// ---------------- transpose+convert: src f32 [R][C] -> dst bf16 [C][ldDst]
struct TPtrs {
    const float* src[12];
    unsigned short* dst[12];
};

__global__ __launch_bounds__(256) void transpose_k(TPtrs tp, int R, int C, int ldDst) {
    const float* __restrict__ src = tp.src[blockIdx.z];
    unsigned short* __restrict__ dst = tp.dst[blockIdx.z];
    __shared__ unsigned short tile[32][33];
    const int tid = threadIdx.x;
    const int tc = tid & 31, tr = tid >> 5;   // tr 0..7
    const int c0 = blockIdx.x * 32, r0 = blockIdx.y * 32;
#pragma unroll
    for (int i = 0; i < 4; ++i) {
        int r = r0 + tr + i * 8, c = c0 + tc;
        unsigned short v = 0;
        if (r < R && c < C) v = f2b(src[(size_t)r * C + c]);
        tile[tr + i * 8][tc] = v;
    }
    __syncthreads();
#pragma unroll
    for (int i = 0; i < 4; ++i) {
        int c = c0 + tr + i * 8;  // dst row
        int r = r0 + tc;          // dst col
        if (c < C && r < R) dst[(size_t)c * ldDst + r] = tile[tc][tr + i * 8];
    }
}

// ---------------- f32 -> bf16 copy (h0) + zero the barrier flags
__global__ __launch_bounds__(256) void f2b_k(const float* __restrict__ src,
                                             unsigned short* __restrict__ dst, int n,
                                             int* __restrict__ bar) {
    int i = blockIdx.x * 256 + threadIdx.x;
    if (i < 1024) bar[i] = 0;
    if (i < n) dst[i] = f2b(src[i]);
}

// ---------------- build X: X[t*B + b][e] (stride 304) = t==0 ? features[b][e] : B_emb[captions[b][t-1]][e]
__global__ __launch_bounds__(256) void build_x(const int* __restrict__ captions,
                                               const float* __restrict__ features,
                                               const float* __restrict__ Bemb,
                                               unsigned short* __restrict__ X) {
    int idx = blockIdx.x * 256 + threadIdx.x;     // over B_*T_*E_
    if (idx >= B_ * T_ * E_) return;
    int r = idx / E_, e = idx - r * E_;
    int t = r >> 6, b = r & 63;                   // r = t*B + b, B=64
    float v;
    if (t == 0) v = features[b * E_ + e];
    else {
        int tok = captions[b * T_ + (t - 1)];
        v = Bemb[(size_t)tok * E_ + e];
    }
    X[(size_t)r * 304 + e] = f2b(v);
}

// ---------------- 128x128 MFMA GEMM: C[M][N] = A[M][K](lda) @ Bt[N][K](ldb)^T + bias(f32)
// batched over blockIdx.z via pointer table. outF32 selects output dtype.
// Optional output-row permute (projection): orow = (r % permB)*permT + r/permB
struct GemmB4 {
    const unsigned short* A[4];
    const unsigned short* Bt[4];
    const float* bias[4];
    void* C[4];
};

__global__ __launch_bounds__(256) void gemm_k(GemmB4 ga, int M, int N, int K,
                                              int lda, int ldb, int permB, int permT,
                                              int outF32) {
    const int g = blockIdx.z;
    const unsigned short* __restrict__ A = ga.A[g];
    const unsigned short* __restrict__ Bt = ga.Bt[g];
    const float* __restrict__ bias = ga.bias[g];
    void* __restrict__ C = ga.C[g];

    const int m0 = blockIdx.y * 128, n0 = blockIdx.x * 128;
    __shared__ unsigned short As[128 * 40];
    __shared__ unsigned short Bs[128 * 40];
    const int tid = threadIdx.x;
    const int lane = tid & 63, wv = tid >> 6;
    const int quad = lane >> 4, l16 = lane & 15;
    const int mw = (wv & 1) * 64, nw = (wv >> 1) * 64;
    const int srow = tid >> 2, scol = (tid & 3) * 8;   // srow 0..63, scol 0..24

    f32x4 acc[4][4] = {};

    for (int k0 = 0; k0 < K; k0 += 32) {
        const int kk = k0 + scol;
#pragma unroll
        for (int half = 0; half < 2; ++half) {
            const int row = srow + half * 64;
            {
                ushort8_t v = {0, 0, 0, 0, 0, 0, 0, 0};
                int gm = m0 + row;
                if (gm < M) {
                    const unsigned short* p = A + (size_t)gm * lda + kk;
                    if (kk + 8 <= K) v = *(const ushort8_t*)p;
                    else {
#pragma unroll
                        for (int jj = 0; jj < 8; ++jj) if (kk + jj < K) v[jj] = p[jj];
                    }
                }
                *(ushort8_t*)&As[row * 40 + scol] = v;
            }
            {
                ushort8_t v = {0, 0, 0, 0, 0, 0, 0, 0};
                int gn = n0 + row;
                if (gn < N) {
                    const unsigned short* p = Bt + (size_t)gn * ldb + kk;
                    if (kk + 8 <= K) v = *(const ushort8_t*)p;
                    else {
#pragma unroll
                        for (int jj = 0; jj < 8; ++jj) if (kk + jj < K) v[jj] = p[jj];
                    }
                }
                *(ushort8_t*)&Bs[row * 40 + scol] = v;
            }
        }
        __syncthreads();
        bf16x8 af[4], bf[4];
#pragma unroll
        for (int mt = 0; mt < 4; ++mt)
            af[mt] = *(const bf16x8*)&As[(mw + mt * 16 + l16) * 40 + quad * 8];
#pragma unroll
        for (int nt = 0; nt < 4; ++nt)
            bf[nt] = *(const bf16x8*)&Bs[(nw + nt * 16 + l16) * 40 + quad * 8];
#pragma unroll
        for (int mt = 0; mt < 4; ++mt)
#pragma unroll
            for (int nt = 0; nt < 4; ++nt)
                acc[mt][nt] = mfma16(af[mt], bf[nt], acc[mt][nt]);
        __syncthreads();
    }

#pragma unroll
    for (int mt = 0; mt < 4; ++mt)
#pragma unroll
        for (int nt = 0; nt < 4; ++nt) {
            int col = n0 + nw + nt * 16 + l16;
            if (col >= N) continue;
            float bv = bias[col];
            int rowb = m0 + mw + mt * 16 + quad * 4;
#pragma unroll
            for (int r = 0; r < 4; ++r) {
                int rr = rowb + r;
                if (rr < M) {
                    float vv = acc[mt][nt][r] + bv;
                    int orow = permT ? ((rr % permB) * permT + rr / permB) : rr;
                    if (outF32) ((float*)C)[(size_t)orow * N + col] = vv;
                    else ((unsigned short*)C)[(size_t)orow * N + col] = f2b(vv);
                }
            }
        }
}

// ---------------- fused persistent LSTM: all 30 steps in one launch.
// Grid = 32 WGs x 256. WG j owns h-cols [j*16, j*16+16). Wave g (=tid>>6) owns gate g.
// Gate-weight A-fragments live in VGPRs (loaded once). c state lives in registers.
// Cross-WG h traffic goes through the coherence point (agent-scope relaxed atomics,
// sc0/sc1 — bypasses the non-coherent per-XCD L2s). Grid barrier = per-WG flag lines
// (one relaxed atomic store each; wave-0 lanes poll all 32 flags with read-only
// atomic loads — no cacheline ownership bouncing, no L2 writeback fences).
struct FusedA {
    const unsigned short* h0;     // [B_][H_] bf16
    const unsigned short* Wt[4];  // [H_][H_] bf16, Wt[n][k] = W[k][n]
    const float* Wb[4];           // [H_] f32
    const unsigned short* U[4];   // [T_*B_][H_] bf16 (chain output, incl. U bias)
    const float* c0;              // [B_][H_] f32
    unsigned short* Hall;         // [T_*B_][H_] bf16 out
    int* bar;                     // 32 flags at 128B stride
};

__global__ __launch_bounds__(256, 1) void lstm_fused(FusedA s) {
    const int j = blockIdx.x;                 // 0..31
    const int tid = threadIdx.x;
    const int g = tid >> 6;                   // wave = gate
    const int lane = tid & 63;
    const int quad = lane >> 4, l16 = lane & 15;
    __shared__ float xch[4][16 * 65];         // [gate][hc_local][batch], padded

    // one-time: gate-g A-fragments for this WG's 16 h-cols (16 k-chunks)
    bf16x8 afrag[16];
    {
        const unsigned short* wt = s.Wt[g] + (size_t)(j * 16 + l16) * H_ + quad * 8;
#pragma unroll
        for (int kc = 0; kc < 16; ++kc)
            afrag[kc] = *(const bf16x8*)(wt + kc * 32);
    }

    // per-thread epilogue assignment: (batch eb, local hcols ehc..ehc+3)
    const int eb = tid >> 2;
    const int ehc = (tid & 3) * 4;
    const int hcg = j * 16 + ehc;             // global hcol base
    f32x4 wb[4];
#pragma unroll
    for (int q = 0; q < 4; ++q) wb[q] = *(const f32x4*)(s.Wb[q] + hcg);
    f32x4 c = *(const f32x4*)(s.c0 + (size_t)eb * H_ + hcg);

    for (int t = 0; t < T_; ++t) {
        const unsigned short* hp = (t == 0) ? s.h0 : (s.Hall + (size_t)(t - 1) * B_ * H_);
        // GEMM: D[hc(16) x b(64)] for gate g, K=512 (h via coherence-point loads)
        f32x4 acc[4] = {{0.f,0.f,0.f,0.f},{0.f,0.f,0.f,0.f},{0.f,0.f,0.f,0.f},{0.f,0.f,0.f,0.f}};
#pragma unroll
        for (int kc = 0; kc < 16; ++kc) {
            const unsigned short* hb = hp + kc * 32 + quad * 8;
#pragma unroll
            for (int nt = 0; nt < 4; ++nt) {
                bf16x8 bfr = load_h16(hb + (size_t)(nt * 16 + l16) * H_);
                acc[nt] = mfma16(afrag[kc], bfr, acc[nt]);
            }
        }
        // exchange gate preacts through LDS
#pragma unroll
        for (int nt = 0; nt < 4; ++nt)
#pragma unroll
            for (int r = 0; r < 4; ++r)
                xch[g][(quad * 4 + r) * 65 + nt * 16 + l16] = acc[nt][r];
        __syncthreads();
        // epilogue: this thread's 4 elements (eb, ehc..+3)
        ushort4_t u[4];
#pragma unroll
        for (int q = 0; q < 4; ++q)
            u[q] = *(const ushort4_t*)(s.U[q] + ((size_t)t * B_ + eb) * H_ + hcg);
        ushort4_t hnew;
#pragma unroll
        for (int r = 0; r < 4; ++r) {
            float pi = xch[0][(ehc + r) * 65 + eb] + b2f(u[0][r]) + wb[0][r];
            float pf = xch[1][(ehc + r) * 65 + eb] + b2f(u[1][r]) + wb[1][r];
            float po = xch[2][(ehc + r) * 65 + eb] + b2f(u[2][r]) + wb[2][r];
            float pc = xch[3][(ehc + r) * 65 + eb] + b2f(u[3][r]) + wb[3][r];
            float it = 1.f / (1.f + __expf(-pi));
            float ft = 1.f / (1.f + __expf(-pf));
            float ot = 1.f / (1.f + __expf(-po));
            float ct = tanhf(pc);
            float cn = ft * c[r] + it * ct;
            c[r] = cn;
            hnew[r] = f2b(ot * cn);
        }
        {
            union { ushort4_t s4; unsigned long long q; } hu;
            hu.s4 = hnew;
            __hip_atomic_store((unsigned long long*)(s.Hall + ((size_t)t * B_ + eb) * H_ + hcg),
                               hu.q, __ATOMIC_RELAXED, __HIP_MEMORY_SCOPE_AGENT);
        }
        if (t + 1 < T_) {
            // drain this wave's h stores to the coherence point, then WG-wide rendezvous
            asm volatile("s_waitcnt vmcnt(0)" ::: "memory");
            __syncthreads();
            if (g == 0) {
                if (lane == 0)
                    __hip_atomic_store(&s.bar[j * 32], t + 1,
                                       __ATOMIC_RELAXED, __HIP_MEMORY_SCOPE_AGENT);
                const int fi = (lane & 31) * 32;
                bool ok;
                do {
                    int v = __hip_atomic_load(&s.bar[fi],
                                              __ATOMIC_RELAXED, __HIP_MEMORY_SCOPE_AGENT);
                    ok = (v >= t + 1);
                } while (!__all(ok));
            }
            __syncthreads();
        }
    }
}

extern "C" void kernel_launch(void* const* d_in, const int* in_sizes, int n_in,
                              void* d_out, int out_size, void* d_ws, size_t ws_size,
                              hipStream_t stream) {
    (void)in_sizes; (void)n_in; (void)out_size; (void)ws_size;
    const int* captions = (const int*)d_in[0];
    const float* features = (const float*)d_in[1];
    const float* h0 = (const float*)d_in[2];
    const float* c0 = (const float*)d_in[3];
    const float* Bemb = (const float*)d_in[4];
    const float *iVW[4], *iVb[4], *iSW[4], *iSb[4], *iUW[4], *iUb[4], *iWW[4], *iWb[4];
    for (int g = 0; g < 4; ++g) {
        const int base = 5 + 8 * g;
        iVW[g] = (const float*)d_in[base + 0];
        iVb[g] = (const float*)d_in[base + 1];
        iSW[g] = (const float*)d_in[base + 2];
        iSb[g] = (const float*)d_in[base + 3];
        iUW[g] = (const float*)d_in[base + 4];
        iUb[g] = (const float*)d_in[base + 5];
        iWW[g] = (const float*)d_in[base + 6];
        iWb[g] = (const float*)d_in[base + 7];
    }
    const float* CW = (const float*)d_in[37];
    const float* Cb = (const float*)d_in[38];

    // ---- workspace carve-up (bytes, 256B aligned)
    char* w = (char*)d_ws;
    auto alloc = [&](size_t bytes) -> void* {
        void* p = (void*)w;
        w += (bytes + 255) & ~(size_t)255;
        return p;
    };
    int* dbar = (int*)alloc(4096);
    unsigned short* cH0 = (unsigned short*)alloc((size_t)B_ * H_ * 2);
    unsigned short *wVt[4], *wSt[4], *wUt[4], *wWt[4];
    for (int g = 0; g < 4; ++g) wVt[g] = (unsigned short*)alloc((size_t)FD_ * 304 * 2);
    for (int g = 0; g < 4; ++g) wSt[g] = (unsigned short*)alloc((size_t)FD_ * FD_ * 2);
    for (int g = 0; g < 4; ++g) wUt[g] = (unsigned short*)alloc((size_t)H_ * FD_ * 2);
    for (int g = 0; g < 4; ++g) wWt[g] = (unsigned short*)alloc((size_t)H_ * H_ * 2);
    unsigned short* wCt = (unsigned short*)alloc((size_t)V_ * H_ * 2);
    unsigned short* wX = (unsigned short*)alloc((size_t)B_ * T_ * 304 * 2);
    unsigned short *bufA[4], *bufB[4];
    for (int g = 0; g < 4; ++g) bufA[g] = (unsigned short*)alloc((size_t)B_ * T_ * FD_ * 2);
    for (int g = 0; g < 4; ++g) bufB[g] = (unsigned short*)alloc((size_t)B_ * T_ * FD_ * 2);
    unsigned short* Hall = (unsigned short*)alloc((size_t)B_ * T_ * H_ * 2);

    // ---- h0 -> bf16 + zero barrier flags
    f2b_k<<<dim3((B_ * H_ + 255) / 256), 256, 0, stream>>>(h0, cH0, B_ * H_, dbar);

    // ---- transposes (f32 -> bf16)
    {
        TPtrs tp{};
        for (int g = 0; g < 4; ++g) {
            tp.src[g * 3 + 0] = iSW[g]; tp.dst[g * 3 + 0] = wSt[g];
            tp.src[g * 3 + 1] = iUW[g]; tp.dst[g * 3 + 1] = wUt[g];
            tp.src[g * 3 + 2] = iWW[g]; tp.dst[g * 3 + 2] = wWt[g];
        }
        transpose_k<<<dim3(16, 16, 12), 256, 0, stream>>>(tp, 512, 512, 512);
    }
    {
        TPtrs tp{};
        for (int g = 0; g < 4; ++g) { tp.src[g] = iVW[g]; tp.dst[g] = wVt[g]; }
        transpose_k<<<dim3(16, 10, 4), 256, 0, stream>>>(tp, E_, FD_, 304);
    }
    {
        TPtrs tp{};
        tp.src[0] = CW; tp.dst[0] = wCt;
        transpose_k<<<dim3(313, 16, 1), 256, 0, stream>>>(tp, H_, V_, H_);
    }

    // ---- build X (time-major rows r = t*B+b, stride 304)
    build_x<<<dim3((B_ * T_ * E_ + 255) / 256), 256, 0, stream>>>(captions, features, Bemb, wX);

    // ---- gate preactivation chain (batched over 4 gates), 128x128 tiles
    {
        GemmB4 ga;
        for (int g = 0; g < 4; ++g) { ga.A[g] = wX; ga.Bt[g] = wVt[g]; ga.bias[g] = iVb[g]; ga.C[g] = bufA[g]; }
        gemm_k<<<dim3(4, 15, 4), 256, 0, stream>>>(ga, B_ * T_, FD_, E_, 304, 304, 0, 0, 0);
    }
    {
        GemmB4 ga;
        for (int g = 0; g < 4; ++g) { ga.A[g] = bufA[g]; ga.Bt[g] = wSt[g]; ga.bias[g] = iSb[g]; ga.C[g] = bufB[g]; }
        gemm_k<<<dim3(4, 15, 4), 256, 0, stream>>>(ga, B_ * T_, FD_, FD_, FD_, FD_, 0, 0, 0);
    }
    {
        GemmB4 ga;
        for (int g = 0; g < 4; ++g) { ga.A[g] = bufB[g]; ga.Bt[g] = wUt[g]; ga.bias[g] = iUb[g]; ga.C[g] = bufA[g]; }
        gemm_k<<<dim3(4, 15, 4), 256, 0, stream>>>(ga, B_ * T_, H_, FD_, FD_, FD_, 0, 0, 0);
    }

    // ---- fused 30-step LSTM (single launch, flag-array grid barrier per step)
    {
        FusedA fa;
        fa.h0 = cH0;
        for (int g = 0; g < 4; ++g) {
            fa.Wt[g] = wWt[g];
            fa.Wb[g] = iWb[g];
            fa.U[g] = bufA[g];
        }
        fa.c0 = c0;
        fa.Hall = Hall;
        fa.bar = dbar;
        lstm_fused<<<dim3(NWG_FUSED), 256, 0, stream>>>(fa);
    }

    // ---- vocab projection for all (t,b), f32 output, permuting rows back to [B][T][V]
    {
        GemmB4 ga{};
        ga.A[0] = Hall; ga.Bt[0] = wCt; ga.bias[0] = Cb; ga.C[0] = d_out;
        gemm_k<<<dim3(79, 15, 1), 256, 0, stream>>>(
            ga, B_ * T_, V_, H_, H_, H_, B_, T_, 1);
    }
}

// Round 6
// 673.946 us; speedup vs baseline: 1.3404x; 1.3404x over previous
//
#include <hip/hip_runtime.h>
#include <hip/hip_bf16.h>

#define B_  64
#define T_  30
#define E_  300
#define H_  512
#define FD_ 512
#define V_  10000
#define NWG_FUSED 32

typedef __attribute__((ext_vector_type(8))) unsigned short ushort8_t;
typedef __attribute__((ext_vector_type(4))) unsigned short ushort4_t;
typedef __attribute__((ext_vector_type(8))) __bf16 bf16x8;
typedef __attribute__((ext_vector_type(4))) float f32x4;

__device__ __forceinline__ float b2f(unsigned short u) {
    union { unsigned int i; float f; } v;
    v.i = ((unsigned int)u) << 16;
    return v.f;
}
__device__ __forceinline__ unsigned short f2b(float f) {
    unsigned int x = __builtin_bit_cast(unsigned int, f);
    unsigned int r = x + 0x7FFFu + ((x >> 16) & 1u);
    return (unsigned short)(r >> 16);
}

__device__ __forceinline__ f32x4 mfma16(bf16x8 a, bf16x8 b, f32x4 c) {
    return __builtin_amdgcn_mfma_f32_16x16x32_bf16(a, b, c, 0, 0, 0);
}

// ---------------- transpose+convert: src f32 [R][C] -> dst bf16 [C][ldDst]
struct TPtrs {
    const float* src[12];
    unsigned short* dst[12];
};

__global__ __launch_bounds__(256) void transpose_k(TPtrs tp, int R, int C, int ldDst) {
    const float* __restrict__ src = tp.src[blockIdx.z];
    unsigned short* __restrict__ dst = tp.dst[blockIdx.z];
    __shared__ unsigned short tile[32][33];
    const int tid = threadIdx.x;
    const int tc = tid & 31, tr = tid >> 5;   // tr 0..7
    const int c0 = blockIdx.x * 32, r0 = blockIdx.y * 32;
#pragma unroll
    for (int i = 0; i < 4; ++i) {
        int r = r0 + tr + i * 8, c = c0 + tc;
        unsigned short v = 0;
        if (r < R && c < C) v = f2b(src[(size_t)r * C + c]);
        tile[tr + i * 8][tc] = v;
    }
    __syncthreads();
#pragma unroll
    for (int i = 0; i < 4; ++i) {
        int c = c0 + tr + i * 8;  // dst row
        int r = r0 + tc;          // dst col
        if (c < C && r < R) dst[(size_t)c * ldDst + r] = tile[tc][tr + i * 8];
    }
}

// ---------------- f32 -> bf16 copy (h0) + zero the barrier flags
__global__ __launch_bounds__(256) void f2b_k(const float* __restrict__ src,
                                             unsigned short* __restrict__ dst, int n,
                                             int* __restrict__ bar) {
    int i = blockIdx.x * 256 + threadIdx.x;
    if (i < 1024) bar[i] = 0;
    if (i < n) dst[i] = f2b(src[i]);
}

// ---------------- build X: X[t*B + b][e] (stride 304) = t==0 ? features[b][e] : B_emb[captions[b][t-1]][e]
__global__ __launch_bounds__(256) void build_x(const int* __restrict__ captions,
                                               const float* __restrict__ features,
                                               const float* __restrict__ Bemb,
                                               unsigned short* __restrict__ X) {
    int idx = blockIdx.x * 256 + threadIdx.x;     // over B_*T_*E_
    if (idx >= B_ * T_ * E_) return;
    int r = idx / E_, e = idx - r * E_;
    int t = r >> 6, b = r & 63;                   // r = t*B + b, B=64
    float v;
    if (t == 0) v = features[b * E_ + e];
    else {
        int tok = captions[b * T_ + (t - 1)];
        v = Bemb[(size_t)tok * E_ + e];
    }
    X[(size_t)r * 304 + e] = f2b(v);
}

// ---------------- 128x128 MFMA GEMM: C[M][N] = A[M][K](lda) @ Bt[N][K](ldb)^T + bias(f32)
// batched over blockIdx.z via pointer table. outF32 selects output dtype.
// Optional output-row permute (projection): orow = (r % permB)*permT + r/permB
struct GemmB4 {
    const unsigned short* A[4];
    const unsigned short* Bt[4];
    const float* bias[4];
    void* C[4];
};

__global__ __launch_bounds__(256) void gemm_k(GemmB4 ga, int M, int N, int K,
                                              int lda, int ldb, int permB, int permT,
                                              int outF32) {
    const int g = blockIdx.z;
    const unsigned short* __restrict__ A = ga.A[g];
    const unsigned short* __restrict__ Bt = ga.Bt[g];
    const float* __restrict__ bias = ga.bias[g];
    void* __restrict__ C = ga.C[g];

    const int m0 = blockIdx.y * 128, n0 = blockIdx.x * 128;
    __shared__ unsigned short As[128 * 40];
    __shared__ unsigned short Bs[128 * 40];
    const int tid = threadIdx.x;
    const int lane = tid & 63, wv = tid >> 6;
    const int quad = lane >> 4, l16 = lane & 15;
    const int mw = (wv & 1) * 64, nw = (wv >> 1) * 64;
    const int srow = tid >> 2, scol = (tid & 3) * 8;   // srow 0..63, scol 0..24

    f32x4 acc[4][4] = {};

    for (int k0 = 0; k0 < K; k0 += 32) {
        const int kk = k0 + scol;
#pragma unroll
        for (int half = 0; half < 2; ++half) {
            const int row = srow + half * 64;
            {
                ushort8_t v = {0, 0, 0, 0, 0, 0, 0, 0};
                int gm = m0 + row;
                if (gm < M) {
                    const unsigned short* p = A + (size_t)gm * lda + kk;
                    if (kk + 8 <= K) v = *(const ushort8_t*)p;
                    else {
#pragma unroll
                        for (int jj = 0; jj < 8; ++jj) if (kk + jj < K) v[jj] = p[jj];
                    }
                }
                *(ushort8_t*)&As[row * 40 + scol] = v;
            }
            {
                ushort8_t v = {0, 0, 0, 0, 0, 0, 0, 0};
                int gn = n0 + row;
                if (gn < N) {
                    const unsigned short* p = Bt + (size_t)gn * ldb + kk;
                    if (kk + 8 <= K) v = *(const ushort8_t*)p;
                    else {
#pragma unroll
                        for (int jj = 0; jj < 8; ++jj) if (kk + jj < K) v[jj] = p[jj];
                    }
                }
                *(ushort8_t*)&Bs[row * 40 + scol] = v;
            }
        }
        __syncthreads();
        bf16x8 af[4], bf[4];
#pragma unroll
        for (int mt = 0; mt < 4; ++mt)
            af[mt] = *(const bf16x8*)&As[(mw + mt * 16 + l16) * 40 + quad * 8];
#pragma unroll
        for (int nt = 0; nt < 4; ++nt)
            bf[nt] = *(const bf16x8*)&Bs[(nw + nt * 16 + l16) * 40 + quad * 8];
#pragma unroll
        for (int mt = 0; mt < 4; ++mt)
#pragma unroll
            for (int nt = 0; nt < 4; ++nt)
                acc[mt][nt] = mfma16(af[mt], bf[nt], acc[mt][nt]);
        __syncthreads();
    }

#pragma unroll
    for (int mt = 0; mt < 4; ++mt)
#pragma unroll
        for (int nt = 0; nt < 4; ++nt) {
            int col = n0 + nw + nt * 16 + l16;
            if (col >= N) continue;
            float bv = bias[col];
            int rowb = m0 + mw + mt * 16 + quad * 4;
#pragma unroll
            for (int r = 0; r < 4; ++r) {
                int rr = rowb + r;
                if (rr < M) {
                    float vv = acc[mt][nt][r] + bv;
                    int orow = permT ? ((rr % permB) * permT + rr / permB) : rr;
                    if (outF32) ((float*)C)[(size_t)orow * N + col] = vv;
                    else ((unsigned short*)C)[(size_t)orow * N + col] = f2b(vv);
                }
            }
        }
}

// ---------------- fused persistent LSTM: all 30 steps in one launch.
// Grid = 32 WGs x 256. WG j owns h-cols [j*16, j*16+16). Wave g (=tid>>6) owns gate g.
// Gate-weight A-fragments live in VGPRs (loaded once). c state lives in registers.
// Producer side: h stored via agent-scope relaxed atomic stores (write-through to
// the coherence point, 8B/thread — tiny). Consumer side: PLAIN cached loads — every
// Hall address is first touched after the barrier, so the L2 fill comes from the
// IF$ which already holds the store (drained by s_waitcnt vmcnt(0) pre-flag).
// Barrier: per-WG flag lines, one relaxed store each; wave-0 lanes poll all 32
// flags with read-only atomic loads (no cacheline ownership bouncing, no fences).
struct FusedA {
    const unsigned short* h0;     // [B_][H_] bf16
    const unsigned short* Wt[4];  // [H_][H_] bf16, Wt[n][k] = W[k][n]
    const float* Wb[4];           // [H_] f32
    const unsigned short* U[4];   // [T_*B_][H_] bf16 (chain output, incl. U bias)
    const float* c0;              // [B_][H_] f32
    unsigned short* Hall;         // [T_*B_][H_] bf16 out
    int* bar;                     // 32 flags at 128B stride
};

__global__ __launch_bounds__(256, 1) void lstm_fused(FusedA s) {
    const int j = blockIdx.x;                 // 0..31
    const int tid = threadIdx.x;
    const int g = tid >> 6;                   // wave = gate
    const int lane = tid & 63;
    const int quad = lane >> 4, l16 = lane & 15;
    __shared__ float xch[4][16 * 65];         // [gate][hc_local][batch], padded

    // one-time: gate-g A-fragments for this WG's 16 h-cols (16 k-chunks)
    bf16x8 afrag[16];
    {
        const unsigned short* wt = s.Wt[g] + (size_t)(j * 16 + l16) * H_ + quad * 8;
#pragma unroll
        for (int kc = 0; kc < 16; ++kc)
            afrag[kc] = *(const bf16x8*)(wt + kc * 32);
    }

    // per-thread epilogue assignment: (batch eb, local hcols ehc..ehc+3)
    const int eb = tid >> 2;
    const int ehc = (tid & 3) * 4;
    const int hcg = j * 16 + ehc;             // global hcol base
    f32x4 wb[4];
#pragma unroll
    for (int q = 0; q < 4; ++q) wb[q] = *(const f32x4*)(s.Wb[q] + hcg);
    f32x4 c = *(const f32x4*)(s.c0 + (size_t)eb * H_ + hcg);

    for (int t = 0; t < T_; ++t) {
        const unsigned short* hp = (t == 0) ? s.h0 : (s.Hall + (size_t)(t - 1) * B_ * H_);
        // GEMM: D[hc(16) x b(64)] for gate g, K=512 — plain cached h loads
        f32x4 acc[4] = {{0.f,0.f,0.f,0.f},{0.f,0.f,0.f,0.f},{0.f,0.f,0.f,0.f},{0.f,0.f,0.f,0.f}};
#pragma unroll
        for (int kc = 0; kc < 16; ++kc) {
            const unsigned short* hb = hp + kc * 32 + quad * 8;
#pragma unroll
            for (int nt = 0; nt < 4; ++nt) {
                bf16x8 bfr = *(const bf16x8*)(hb + (size_t)(nt * 16 + l16) * H_);
                acc[nt] = mfma16(afrag[kc], bfr, acc[nt]);
            }
        }
        // exchange gate preacts through LDS
#pragma unroll
        for (int nt = 0; nt < 4; ++nt)
#pragma unroll
            for (int r = 0; r < 4; ++r)
                xch[g][(quad * 4 + r) * 65 + nt * 16 + l16] = acc[nt][r];
        __syncthreads();
        // epilogue: this thread's 4 elements (eb, ehc..+3)
        ushort4_t u[4];
#pragma unroll
        for (int q = 0; q < 4; ++q)
            u[q] = *(const ushort4_t*)(s.U[q] + ((size_t)t * B_ + eb) * H_ + hcg);
        ushort4_t hnew;
#pragma unroll
        for (int r = 0; r < 4; ++r) {
            float pi = xch[0][(ehc + r) * 65 + eb] + b2f(u[0][r]) + wb[0][r];
            float pf = xch[1][(ehc + r) * 65 + eb] + b2f(u[1][r]) + wb[1][r];
            float po = xch[2][(ehc + r) * 65 + eb] + b2f(u[2][r]) + wb[2][r];
            float pc = xch[3][(ehc + r) * 65 + eb] + b2f(u[3][r]) + wb[3][r];
            float it = 1.f / (1.f + __expf(-pi));
            float ft = 1.f / (1.f + __expf(-pf));
            float ot = 1.f / (1.f + __expf(-po));
            float ct = tanhf(pc);
            float cn = ft * c[r] + it * ct;
            c[r] = cn;
            hnew[r] = f2b(ot * cn);
        }
        {
            union { ushort4_t s4; unsigned long long q; } hu;
            hu.s4 = hnew;
            __hip_atomic_store((unsigned long long*)(s.Hall + ((size_t)t * B_ + eb) * H_ + hcg),
                               hu.q, __ATOMIC_RELAXED, __HIP_MEMORY_SCOPE_AGENT);
        }
        if (t + 1 < T_) {
            // drain this wave's h stores to the coherence point, then WG-wide rendezvous
            asm volatile("s_waitcnt vmcnt(0)" ::: "memory");
            __syncthreads();
            if (g == 0) {
                if (lane == 0)
                    __hip_atomic_store(&s.bar[j * 32], t + 1,
                                       __ATOMIC_RELAXED, __HIP_MEMORY_SCOPE_AGENT);
                const int fi = (lane & 31) * 32;
                bool ok;
                do {
                    int v = __hip_atomic_load(&s.bar[fi],
                                              __ATOMIC_RELAXED, __HIP_MEMORY_SCOPE_AGENT);
                    ok = (v >= t + 1);
                } while (!__all(ok));
            }
            __syncthreads();
        }
    }
}

extern "C" void kernel_launch(void* const* d_in, const int* in_sizes, int n_in,
                              void* d_out, int out_size, void* d_ws, size_t ws_size,
                              hipStream_t stream) {
    (void)in_sizes; (void)n_in; (void)out_size; (void)ws_size;
    const int* captions = (const int*)d_in[0];
    const float* features = (const float*)d_in[1];
    const float* h0 = (const float*)d_in[2];
    const float* c0 = (const float*)d_in[3];
    const float* Bemb = (const float*)d_in[4];
    const float *iVW[4], *iVb[4], *iSW[4], *iSb[4], *iUW[4], *iUb[4], *iWW[4], *iWb[4];
    for (int g = 0; g < 4; ++g) {
        const int base = 5 + 8 * g;
        iVW[g] = (const float*)d_in[base + 0];
        iVb[g] = (const float*)d_in[base + 1];
        iSW[g] = (const float*)d_in[base + 2];
        iSb[g] = (const float*)d_in[base + 3];
        iUW[g] = (const float*)d_in[base + 4];
        iUb[g] = (const float*)d_in[base + 5];
        iWW[g] = (const float*)d_in[base + 6];
        iWb[g] = (const float*)d_in[base + 7];
    }
    const float* CW = (const float*)d_in[37];
    const float* Cb = (const float*)d_in[38];

    // ---- workspace carve-up (bytes, 256B aligned)
    char* w = (char*)d_ws;
    auto alloc = [&](size_t bytes) -> void* {
        void* p = (void*)w;
        w += (bytes + 255) & ~(size_t)255;
        return p;
    };
    int* dbar = (int*)alloc(4096);
    unsigned short* cH0 = (unsigned short*)alloc((size_t)B_ * H_ * 2);
    unsigned short *wVt[4], *wSt[4], *wUt[4], *wWt[4];
    for (int g = 0; g < 4; ++g) wVt[g] = (unsigned short*)alloc((size_t)FD_ * 304 * 2);
    for (int g = 0; g < 4; ++g) wSt[g] = (unsigned short*)alloc((size_t)FD_ * FD_ * 2);
    for (int g = 0; g < 4; ++g) wUt[g] = (unsigned short*)alloc((size_t)H_ * FD_ * 2);
    for (int g = 0; g < 4; ++g) wWt[g] = (unsigned short*)alloc((size_t)H_ * H_ * 2);
    unsigned short* wCt = (unsigned short*)alloc((size_t)V_ * H_ * 2);
    unsigned short* wX = (unsigned short*)alloc((size_t)B_ * T_ * 304 * 2);
    unsigned short *bufA[4], *bufB[4];
    for (int g = 0; g < 4; ++g) bufA[g] = (unsigned short*)alloc((size_t)B_ * T_ * FD_ * 2);
    for (int g = 0; g < 4; ++g) bufB[g] = (unsigned short*)alloc((size_t)B_ * T_ * FD_ * 2);
    unsigned short* Hall = (unsigned short*)alloc((size_t)B_ * T_ * H_ * 2);

    // ---- h0 -> bf16 + zero barrier flags
    f2b_k<<<dim3((B_ * H_ + 255) / 256), 256, 0, stream>>>(h0, cH0, B_ * H_, dbar);

    // ---- transposes (f32 -> bf16)
    {
        TPtrs tp{};
        for (int g = 0; g < 4; ++g) {
            tp.src[g * 3 + 0] = iSW[g]; tp.dst[g * 3 + 0] = wSt[g];
            tp.src[g * 3 + 1] = iUW[g]; tp.dst[g * 3 + 1] = wUt[g];
            tp.src[g * 3 + 2] = iWW[g]; tp.dst[g * 3 + 2] = wWt[g];
        }
        transpose_k<<<dim3(16, 16, 12), 256, 0, stream>>>(tp, 512, 512, 512);
    }
    {
        TPtrs tp{};
        for (int g = 0; g < 4; ++g) { tp.src[g] = iVW[g]; tp.dst[g] = wVt[g]; }
        transpose_k<<<dim3(16, 10, 4), 256, 0, stream>>>(tp, E_, FD_, 304);
    }
    {
        TPtrs tp{};
        tp.src[0] = CW; tp.dst[0] = wCt;
        transpose_k<<<dim3(313, 16, 1), 256, 0, stream>>>(tp, H_, V_, H_);
    }

    // ---- build X (time-major rows r = t*B+b, stride 304)
    build_x<<<dim3((B_ * T_ * E_ + 255) / 256), 256, 0, stream>>>(captions, features, Bemb, wX);

    // ---- gate preactivation chain (batched over 4 gates), 128x128 tiles
    {
        GemmB4 ga;
        for (int g = 0; g < 4; ++g) { ga.A[g] = wX; ga.Bt[g] = wVt[g]; ga.bias[g] = iVb[g]; ga.C[g] = bufA[g]; }
        gemm_k<<<dim3(4, 15, 4), 256, 0, stream>>>(ga, B_ * T_, FD_, E_, 304, 304, 0, 0, 0);
    }
    {
        GemmB4 ga;
        for (int g = 0; g < 4; ++g) { ga.A[g] = bufA[g]; ga.Bt[g] = wSt[g]; ga.bias[g] = iSb[g]; ga.C[g] = bufB[g]; }
        gemm_k<<<dim3(4, 15, 4), 256, 0, stream>>>(ga, B_ * T_, FD_, FD_, FD_, FD_, 0, 0, 0);
    }
    {
        GemmB4 ga;
        for (int g = 0; g < 4; ++g) { ga.A[g] = bufB[g]; ga.Bt[g] = wUt[g]; ga.bias[g] = iUb[g]; ga.C[g] = bufA[g]; }
        gemm_k<<<dim3(4, 15, 4), 256, 0, stream>>>(ga, B_ * T_, H_, FD_, FD_, FD_, 0, 0, 0);
    }

    // ---- fused 30-step LSTM (single launch, flag-array grid barrier per step)
    {
        FusedA fa;
        fa.h0 = cH0;
        for (int g = 0; g < 4; ++g) {
            fa.Wt[g] = wWt[g];
            fa.Wb[g] = iWb[g];
            fa.U[g] = bufA[g];
        }
        fa.c0 = c0;
        fa.Hall = Hall;
        fa.bar = dbar;
        lstm_fused<<<dim3(NWG_FUSED), 256, 0, stream>>>(fa);
    }

    // ---- vocab projection for all (t,b), f32 output, permuting rows back to [B][T][V]
    {
        GemmB4 ga{};
        ga.A[0] = Hall; ga.Bt[0] = wCt; ga.bias[0] = Cb; ga.C[0] = d_out;
        gemm_k<<<dim3(79, 15, 1), 256, 0, stream>>>(
            ga, B_ * T_, V_, H_, H_, H_, B_, T_, 1);
    }
}

// Round 8
// 427.014 us; speedup vs baseline: 2.1155x; 1.5783x over previous
//
#include <hip/hip_runtime.h>
#include <hip/hip_bf16.h>

#define B_  64
#define T_  30
#define E_  300
#define H_  512
#define FD_ 512
#define V_  10000
#define NR_ 32          // recurrence WGs
#define NPW_ 224        // projection WGs
#define NTN_ 79         // N tiles of 128 covering V=10000

typedef __attribute__((ext_vector_type(8))) unsigned short ushort8_t;
typedef __attribute__((ext_vector_type(4))) unsigned short ushort4_t;
typedef __attribute__((ext_vector_type(8))) __bf16 bf16x8;
typedef __attribute__((ext_vector_type(4))) float f32x4;

__device__ __forceinline__ float b2f(unsigned short u) {
    union { unsigned int i; float f; } v;
    v.i = ((unsigned int)u) << 16;
    return v.f;
}
__device__ __forceinline__ unsigned short f2b(float f) {
    unsigned int x = __builtin_bit_cast(unsigned int, f);
    unsigned int r = x + 0x7FFFu + ((x >> 16) & 1u);
    return (unsigned short)(r >> 16);
}
__device__ __forceinline__ f32x4 mfma16(bf16x8 a, bf16x8 b, f32x4 c) {
    return __builtin_amdgcn_mfma_f32_16x16x32_bf16(a, b, c, 0, 0, 0);
}

// ================= prep: all transposes + build_x + h0 conv + flag zero =================
// block ranges: [0,3072) 12x 512x512 transposes; [3072,3712) 4x V transposes (R=300,
// Rpad=320, ld=320); [3712,8720) CW transpose (C=10000); [8720,11000) build_x;
// [11000,11128) h0 f2b (32768 elems needs 128 blocks!) + barrier-flag zero.
struct PrepA {
    const float* tsrc[17];
    unsigned short* tdst[17];
    const int* captions;
    const float* features;
    const float* Bemb;
    unsigned short* X;          // stride 304
    const float* h0;
    unsigned short* cH0;
    int* bar;
};

__global__ __launch_bounds__(256) void prep_k(PrepA p) {
    const int blk = blockIdx.x, tid = threadIdx.x;
    __shared__ unsigned short tile[32][33];
    if (blk < 8720) {
        int z, bx, by, R, C, Rpad, ld;
        if (blk < 3072) { z = blk >> 8; int wq = blk & 255; bx = wq & 15; by = wq >> 4; R = 512; C = 512; Rpad = 512; ld = 512; }
        else if (blk < 3712) { int b2 = blk - 3072; z = 12 + b2 / 160; int wq = b2 % 160; bx = wq & 15; by = wq >> 4; R = 300; C = 512; Rpad = 320; ld = 320; }
        else { int b2 = blk - 3712; z = 16; bx = b2 % 313; by = b2 / 313; R = 512; C = 10000; Rpad = 512; ld = 512; }
        const float* __restrict__ src = p.tsrc[z];
        unsigned short* __restrict__ dst = p.tdst[z];
        const int tc = tid & 31, tr = tid >> 5;
        const int c0 = bx * 32, r0 = by * 32;
#pragma unroll
        for (int i = 0; i < 4; ++i) {
            int r = r0 + tr + i * 8, c = c0 + tc;
            unsigned short v = 0;
            if (r < R && c < C) v = f2b(src[(size_t)r * C + c]);
            tile[tr + i * 8][tc] = v;
        }
        __syncthreads();
#pragma unroll
        for (int i = 0; i < 4; ++i) {
            int c = c0 + tr + i * 8;
            int r = r0 + tc;
            if (c < C && r < Rpad) dst[(size_t)c * ld + r] = tile[tc][tr + i * 8];
        }
    } else if (blk < 11000) {
        int idx = (blk - 8720) * 256 + tid;          // over B*T*304
        if (idx < B_ * T_ * 304) {
            int r = idx / 304, e = idx - r * 304;
            int t = r >> 6, b = r & 63;
            float v = 0.f;
            if (e < E_) {
                if (t == 0) v = p.features[b * E_ + e];
                else {
                    int tok = p.captions[b * T_ + (t - 1)];
                    v = p.Bemb[(size_t)tok * E_ + e];
                }
            }
            p.X[(size_t)r * 304 + e] = f2b(v);
        }
    } else {
        int i = (blk - 11000) * 256 + tid;           // 128 blocks -> 32768 threads
        if (i < 1024) p.bar[i] = 0;
        if (i < B_ * H_) p.cH0[i] = f2b(p.h0[i]);
    }
}

// ================= chain: fused 3-stage gate preactivation =================
// WG = (rowblock rb<30) x (gate g). Rows are independent across stages, so each WG
// runs X->V->S->U entirely through LDS ping-pong (no grid sync). Weights from L2.
struct ChainA {
    const unsigned short* X;      // [1920][304]
    const unsigned short* Vt[4];  // [512][320] (zero-padded K)
    const float* Vb[4];
    const unsigned short* St[4];  // [512][512]
    const float* Sb[4];
    const unsigned short* Ut[4];  // [512][512]
    const float* Ub[4];
    unsigned short* U[4];         // out [1920][512] bf16
};

__global__ __launch_bounds__(256) void chain_k(ChainA ca) {
    const int rb = blockIdx.x >> 2, g = blockIdx.x & 3;
    __shared__ char pool[133120];
    unsigned short* XT = (unsigned short*)pool;             // stage A in, stride 328
    unsigned short* R0 = (unsigned short*)pool;             // stage B out, stride 520
    unsigned short* R1 = (unsigned short*)(pool + 66560);   // stage A out, stride 520
    const int tid = threadIdx.x;
    const int wv = tid >> 6, lane = tid & 63;
    const int quad = lane >> 4, l16 = lane & 15;

    // stage X tile (64 rows x 320 cols, zero-padded) into LDS
    {
        const unsigned short* src = ca.X + (size_t)rb * 64 * 304;
#pragma unroll
        for (int it = 0; it < 10; ++it) {
            int id = it * 256 + tid;                        // 2560 chunks of 8
            int row = id / 40, c8 = (id % 40) * 8;
            ushort8_t v = {0, 0, 0, 0, 0, 0, 0, 0};
            if (c8 < 304) v = *(const ushort8_t*)(src + row * 304 + c8);
            *(ushort8_t*)&XT[row * 328 + c8] = v;
        }
    }
    __syncthreads();
    // ---- stage A: R1 = X @ Vt^T + Vb  (K=320 padded)
#pragma unroll
    for (int half = 0; half < 2; ++half) {
        const int cb = wv * 128 + half * 64;
        f32x4 acc[4][4] = {};
        for (int kc = 0; kc < 10; ++kc) {
            bf16x8 af[4];
#pragma unroll
            for (int mt = 0; mt < 4; ++mt)
                af[mt] = *(const bf16x8*)&XT[(mt * 16 + l16) * 328 + kc * 32 + quad * 8];
#pragma unroll
            for (int nt = 0; nt < 4; ++nt) {
                bf16x8 bf = *(const bf16x8*)(ca.Vt[g] + (size_t)(cb + nt * 16 + l16) * 320 + kc * 32 + quad * 8);
#pragma unroll
                for (int mt = 0; mt < 4; ++mt) acc[mt][nt] = mfma16(af[mt], bf, acc[mt][nt]);
            }
        }
#pragma unroll
        for (int mt = 0; mt < 4; ++mt)
#pragma unroll
            for (int nt = 0; nt < 4; ++nt) {
                int col = cb + nt * 16 + l16;
                float bv = ca.Vb[g][col];
#pragma unroll
                for (int r = 0; r < 4; ++r)
                    R1[(mt * 16 + quad * 4 + r) * 520 + col] = f2b(acc[mt][nt][r] + bv);
            }
    }
    __syncthreads();
    // ---- stage B: R0 = R1 @ St^T + Sb  (K=512)
#pragma unroll
    for (int half = 0; half < 2; ++half) {
        const int cb = wv * 128 + half * 64;
        f32x4 acc[4][4] = {};
        for (int kc = 0; kc < 16; ++kc) {
            bf16x8 af[4];
#pragma unroll
            for (int mt = 0; mt < 4; ++mt)
                af[mt] = *(const bf16x8*)&R1[(mt * 16 + l16) * 520 + kc * 32 + quad * 8];
#pragma unroll
            for (int nt = 0; nt < 4; ++nt) {
                bf16x8 bf = *(const bf16x8*)(ca.St[g] + (size_t)(cb + nt * 16 + l16) * 512 + kc * 32 + quad * 8);
#pragma unroll
                for (int mt = 0; mt < 4; ++mt) acc[mt][nt] = mfma16(af[mt], bf, acc[mt][nt]);
            }
        }
        __syncthreads();   // R0 aliases XT region; ensure pool reads done before overwrite
#pragma unroll
        for (int mt = 0; mt < 4; ++mt)
#pragma unroll
            for (int nt = 0; nt < 4; ++nt) {
                int col = cb + nt * 16 + l16;
                float bv = ca.Sb[g][col];
#pragma unroll
                for (int r = 0; r < 4; ++r)
                    R0[(mt * 16 + quad * 4 + r) * 520 + col] = f2b(acc[mt][nt][r] + bv);
            }
    }
    __syncthreads();
    // ---- stage C: global U = R0 @ Ut^T + Ub
#pragma unroll
    for (int half = 0; half < 2; ++half) {
        const int cb = wv * 128 + half * 64;
        f32x4 acc[4][4] = {};
        for (int kc = 0; kc < 16; ++kc) {
            bf16x8 af[4];
#pragma unroll
            for (int mt = 0; mt < 4; ++mt)
                af[mt] = *(const bf16x8*)&R0[(mt * 16 + l16) * 520 + kc * 32 + quad * 8];
#pragma unroll
            for (int nt = 0; nt < 4; ++nt) {
                bf16x8 bf = *(const bf16x8*)(ca.Ut[g] + (size_t)(cb + nt * 16 + l16) * 512 + kc * 32 + quad * 8);
#pragma unroll
                for (int mt = 0; mt < 4; ++mt) acc[mt][nt] = mfma16(af[mt], bf, acc[mt][nt]);
            }
        }
#pragma unroll
        for (int mt = 0; mt < 4; ++mt)
#pragma unroll
            for (int nt = 0; nt < 4; ++nt) {
                int col = cb + nt * 16 + l16;
                float bv = ca.Ub[g][col];
#pragma unroll
                for (int r = 0; r < 4; ++r)
                    ca.U[g][(size_t)(rb * 64 + mt * 16 + quad * 4 + r) * 512 + col] =
                        f2b(acc[mt][nt][r] + bv);
            }
    }
}

// ================= mega: recurrence (32 WGs) + flag-gated projection (224 WGs) =================
struct MegaA {
    const unsigned short* h0c;    // [B][H] bf16
    const unsigned short* Wt[4];  // [512][512]
    const float* Wb[4];
    const unsigned short* U[4];   // [1920][512] bf16
    const float* c0;              // f32
    unsigned short* Hall;         // [1920][512] bf16
    int* bar;                     // 32 flags at 128B stride
    const unsigned short* Ct;     // [10000][512] bf16
    const float* Cb;
    float* out;                   // [B][T][V] f32
};

__global__ __launch_bounds__(256, 1) void mega_k(MegaA a) {
    __shared__ char pool[83712];
    const int tid = threadIdx.x;
    const int lane = tid & 63;
    const int quad = lane >> 4, l16 = lane & 15;

    if (blockIdx.x < NR_) {
        // -------- recurrence WG: owns h-cols [j*16, j*16+16), wave g = gate
        unsigned short* hs = (unsigned short*)pool;       // 64 x 520
        float* xch = (float*)(pool + 66560);              // [4][16*65]
        const int j = blockIdx.x;
        const int g = tid >> 6;
        bf16x8 afrag[16];
        {
            const unsigned short* wt = a.Wt[g] + (size_t)(j * 16 + l16) * H_ + quad * 8;
#pragma unroll
            for (int kc = 0; kc < 16; ++kc) afrag[kc] = *(const bf16x8*)(wt + kc * 32);
        }
        const int eb = tid >> 2;
        const int ehc = (tid & 3) * 4;
        const int hcg = j * 16 + ehc;
        f32x4 wb[4];
#pragma unroll
        for (int q = 0; q < 4; ++q) wb[q] = *(const f32x4*)(a.Wb[q] + hcg);
        f32x4 c = *(const f32x4*)(a.c0 + (size_t)eb * H_ + hcg);

        for (int t = 0; t < T_; ++t) {
            // prefetch U for this step (h-independent)
            ushort4_t u[4];
#pragma unroll
            for (int q = 0; q < 4; ++q)
                u[q] = *(const ushort4_t*)(a.U[q] + ((size_t)t * B_ + eb) * H_ + hcg);
            // stage full h into LDS (wide cooperative load -> max MLP)
            const unsigned short* hp = t ? (a.Hall + (size_t)(t - 1) * B_ * H_) : a.h0c;
#pragma unroll
            for (int it = 0; it < 16; ++it) {
                int id = it * 256 + tid;
                int row = id >> 6, c8 = (id & 63) * 8;
                ushort8_t v = *(const ushort8_t*)(hp + row * H_ + c8);
                *(ushort8_t*)&hs[row * 520 + c8] = v;
            }
            __syncthreads();
            f32x4 acc[4] = {{0.f,0.f,0.f,0.f},{0.f,0.f,0.f,0.f},{0.f,0.f,0.f,0.f},{0.f,0.f,0.f,0.f}};
#pragma unroll
            for (int kc = 0; kc < 16; ++kc) {
#pragma unroll
                for (int nt = 0; nt < 4; ++nt) {
                    bf16x8 bfr = *(const bf16x8*)&hs[(nt * 16 + l16) * 520 + kc * 32 + quad * 8];
                    acc[nt] = mfma16(afrag[kc], bfr, acc[nt]);
                }
            }
#pragma unroll
            for (int nt = 0; nt < 4; ++nt)
#pragma unroll
                for (int r = 0; r < 4; ++r)
                    xch[g * 1040 + (quad * 4 + r) * 65 + nt * 16 + l16] = acc[nt][r];
            __syncthreads();
            ushort4_t hnew;
#pragma unroll
            for (int r = 0; r < 4; ++r) {
                float pi = xch[0 * 1040 + (ehc + r) * 65 + eb] + b2f(u[0][r]) + wb[0][r];
                float pf = xch[1 * 1040 + (ehc + r) * 65 + eb] + b2f(u[1][r]) + wb[1][r];
                float po = xch[2 * 1040 + (ehc + r) * 65 + eb] + b2f(u[2][r]) + wb[2][r];
                float pc = xch[3 * 1040 + (ehc + r) * 65 + eb] + b2f(u[3][r]) + wb[3][r];
                float it = 1.f / (1.f + __expf(-pi));
                float ft = 1.f / (1.f + __expf(-pf));
                float ot = 1.f / (1.f + __expf(-po));
                float ct = tanhf(pc);
                float cn = ft * c[r] + it * ct;
                c[r] = cn;
                hnew[r] = f2b(ot * cn);
            }
            {
                union { ushort4_t s4; unsigned long long q; } hu;
                hu.s4 = hnew;
                __hip_atomic_store((unsigned long long*)(a.Hall + ((size_t)t * B_ + eb) * H_ + hcg),
                                   hu.q, __ATOMIC_RELAXED, __HIP_MEMORY_SCOPE_AGENT);
            }
            asm volatile("s_waitcnt vmcnt(0)" ::: "memory");
            __syncthreads();   // all waves' h stores drained
            if (tid == 0)
                __hip_atomic_store(&a.bar[j * 32], t + 1, __ATOMIC_RELAXED, __HIP_MEMORY_SCOPE_AGENT);
            if (t + 1 < T_) {
                if (g == 0) {
                    const int fi = (lane & 31) * 32;
                    bool done;
                    do {
                        int v = __hip_atomic_load(&a.bar[fi], __ATOMIC_RELAXED, __HIP_MEMORY_SCOPE_AGENT);
                        done = __all(v >= t + 1);
                        if (!done) __builtin_amdgcn_s_sleep(1);
                    } while (!done);
                }
                __syncthreads();
            }
        }
    } else {
        // -------- projection WG: 64x128 tiles of d_out, gated on recurrence flags
        unsigned short* As = (unsigned short*)pool;            // 64 x 40
        unsigned short* Bs = (unsigned short*)(pool + 5120);   // 128 x 40
        const int wv = tid >> 6;
        const int mw = (wv & 1) * 32, nw = (wv >> 1) * 64;
        const int srow = tid >> 2, scol = (tid & 3) * 8;
        int lastT = -1;
        for (int q = (int)blockIdx.x - NR_; q < T_ * NTN_; q += NPW_) {
            const int t = q / NTN_, n0 = (q % NTN_) * 128;
            if (t != lastT) {
                if (tid < 64) {
                    const int fi = (lane & 31) * 32;
                    bool done;
                    do {
                        int v = __hip_atomic_load(&a.bar[fi], __ATOMIC_RELAXED, __HIP_MEMORY_SCOPE_AGENT);
                        done = __all(v >= t + 1);
                        if (!done) __builtin_amdgcn_s_sleep(8);
                    } while (!done);
                }
                __syncthreads();
                lastT = t;
            }
            const unsigned short* A = a.Hall + (size_t)t * B_ * H_;
            f32x4 acc[2][4] = {};
            for (int k0 = 0; k0 < H_; k0 += 32) {
                *(ushort8_t*)&As[srow * 40 + scol] = *(const ushort8_t*)(A + (size_t)srow * H_ + k0 + scol);
#pragma unroll
                for (int half = 0; half < 2; ++half) {
                    int row = srow + half * 64;
                    int gn = n0 + row;
                    ushort8_t v = {0, 0, 0, 0, 0, 0, 0, 0};
                    if (gn < V_) v = *(const ushort8_t*)(a.Ct + (size_t)gn * H_ + k0 + scol);
                    *(ushort8_t*)&Bs[row * 40 + scol] = v;
                }
                __syncthreads();
                bf16x8 af[2], bf[4];
#pragma unroll
                for (int mt = 0; mt < 2; ++mt)
                    af[mt] = *(const bf16x8*)&As[(mw + mt * 16 + l16) * 40 + quad * 8];
#pragma unroll
                for (int nt = 0; nt < 4; ++nt)
                    bf[nt] = *(const bf16x8*)&Bs[(nw + nt * 16 + l16) * 40 + quad * 8];
#pragma unroll
                for (int mt = 0; mt < 2; ++mt)
#pragma unroll
                    for (int nt = 0; nt < 4; ++nt)
                        acc[mt][nt] = mfma16(af[mt], bf[nt], acc[mt][nt]);
                __syncthreads();
            }
#pragma unroll
            for (int mt = 0; mt < 2; ++mt)
#pragma unroll
                for (int nt = 0; nt < 4; ++nt) {
                    int col = n0 + nw + nt * 16 + l16;
                    if (col >= V_) continue;
                    float bv = a.Cb[col];
                    int bb = mw + mt * 16 + quad * 4;
#pragma unroll
                    for (int r = 0; r < 4; ++r) {
                        int orow = (bb + r) * T_ + t;
                        a.out[(size_t)orow * V_ + col] = acc[mt][nt][r] + bv;
                    }
                }
        }
    }
}

extern "C" void kernel_launch(void* const* d_in, const int* in_sizes, int n_in,
                              void* d_out, int out_size, void* d_ws, size_t ws_size,
                              hipStream_t stream) {
    (void)in_sizes; (void)n_in; (void)out_size; (void)ws_size;
    const int* captions = (const int*)d_in[0];
    const float* features = (const float*)d_in[1];
    const float* h0 = (const float*)d_in[2];
    const float* c0 = (const float*)d_in[3];
    const float* Bemb = (const float*)d_in[4];
    const float *iVW[4], *iVb[4], *iSW[4], *iSb[4], *iUW[4], *iUb[4], *iWW[4], *iWb[4];
    for (int g = 0; g < 4; ++g) {
        const int base = 5 + 8 * g;
        iVW[g] = (const float*)d_in[base + 0];
        iVb[g] = (const float*)d_in[base + 1];
        iSW[g] = (const float*)d_in[base + 2];
        iSb[g] = (const float*)d_in[base + 3];
        iUW[g] = (const float*)d_in[base + 4];
        iUb[g] = (const float*)d_in[base + 5];
        iWW[g] = (const float*)d_in[base + 6];
        iWb[g] = (const float*)d_in[base + 7];
    }
    const float* CW = (const float*)d_in[37];
    const float* Cb = (const float*)d_in[38];

    char* w = (char*)d_ws;
    auto alloc = [&](size_t bytes) -> void* {
        void* p = (void*)w;
        w += (bytes + 255) & ~(size_t)255;
        return p;
    };
    int* dbar = (int*)alloc(4096);
    unsigned short* cH0 = (unsigned short*)alloc((size_t)B_ * H_ * 2);
    unsigned short *wVt[4], *wSt[4], *wUt[4], *wWt[4];
    for (int g = 0; g < 4; ++g) wVt[g] = (unsigned short*)alloc((size_t)FD_ * 320 * 2);
    for (int g = 0; g < 4; ++g) wSt[g] = (unsigned short*)alloc((size_t)FD_ * FD_ * 2);
    for (int g = 0; g < 4; ++g) wUt[g] = (unsigned short*)alloc((size_t)H_ * FD_ * 2);
    for (int g = 0; g < 4; ++g) wWt[g] = (unsigned short*)alloc((size_t)H_ * H_ * 2);
    unsigned short* wCt = (unsigned short*)alloc((size_t)V_ * H_ * 2);
    unsigned short* wX = (unsigned short*)alloc((size_t)B_ * T_ * 304 * 2);
    unsigned short* bufA[4];
    for (int g = 0; g < 4; ++g) bufA[g] = (unsigned short*)alloc((size_t)B_ * T_ * FD_ * 2);
    unsigned short* Hall = (unsigned short*)alloc((size_t)B_ * T_ * H_ * 2);

    // ---- dispatch 1: prep (transposes + build_x + h0 + flags)
    {
        PrepA p{};
        for (int g = 0; g < 4; ++g) {
            p.tsrc[g * 3 + 0] = iSW[g]; p.tdst[g * 3 + 0] = wSt[g];
            p.tsrc[g * 3 + 1] = iUW[g]; p.tdst[g * 3 + 1] = wUt[g];
            p.tsrc[g * 3 + 2] = iWW[g]; p.tdst[g * 3 + 2] = wWt[g];
            p.tsrc[12 + g] = iVW[g];    p.tdst[12 + g] = wVt[g];
        }
        p.tsrc[16] = CW; p.tdst[16] = wCt;
        p.captions = captions; p.features = features; p.Bemb = Bemb; p.X = wX;
        p.h0 = h0; p.cH0 = cH0; p.bar = dbar;
        prep_k<<<dim3(11128), 256, 0, stream>>>(p);
    }

    // ---- dispatch 2: fused 3-stage chain
    {
        ChainA ca{};
        ca.X = wX;
        for (int g = 0; g < 4; ++g) {
            ca.Vt[g] = wVt[g]; ca.Vb[g] = iVb[g];
            ca.St[g] = wSt[g]; ca.Sb[g] = iSb[g];
            ca.Ut[g] = wUt[g]; ca.Ub[g] = iUb[g];
            ca.U[g] = bufA[g];
        }
        chain_k<<<dim3(120), 256, 0, stream>>>(ca);
    }

    // ---- dispatch 3: mega (recurrence + overlapped projection)
    {
        MegaA ma{};
        ma.h0c = cH0;
        for (int g = 0; g < 4; ++g) {
            ma.Wt[g] = wWt[g]; ma.Wb[g] = iWb[g]; ma.U[g] = bufA[g];
        }
        ma.c0 = c0;
        ma.Hall = Hall;
        ma.bar = dbar;
        ma.Ct = wCt;
        ma.Cb = Cb;
        ma.out = (float*)d_out;
        mega_k<<<dim3(NR_ + NPW_), 256, 0, stream>>>(ma);
    }
}